// Round 3
// baseline (340.377 us; speedup 1.0000x reference)
//
#include <hip/hip_runtime.h>

typedef unsigned short u16;
typedef unsigned int u32;
typedef __bf16 v8bf __attribute__((ext_vector_type(8)));
typedef float v4f __attribute__((ext_vector_type(4)));

#define DEV __device__ __forceinline__

constexpr int CB = 4;     // batch
constexpr int C = 256;    // channels
constexpr int NN = 4096;  // voxels
constexpr float LOG2E = 1.4426950408889634f;

DEV u16 f2bf(float f) {
  union { float f; u32 u; } v; v.f = f;
  u32 r = v.u + 0x7fffu + ((v.u >> 16) & 1u);  // RNE
  return (u16)(r >> 16);
}
DEV float bf2f(u16 h) {
  union { u32 u; float f; } v; v.u = ((u32)h) << 16; return v.f;
}

// async global->LDS DMA, 16B per lane; LDS dest = wave-uniform base + lane*16
DEV void dma16(const u16* g, const u16* lds_base) {
  __builtin_amdgcn_global_load_lds(
      (const __attribute__((address_space(1))) void*)(unsigned long long)g,
      (__attribute__((address_space(3))) void*)(u32)(unsigned long long)lds_base,
      16, 0, 0);
}

// ---------- transpose + bf16 convert: xT[b][n][c] = bf16(x[b][c][n]) ----------
__global__ __launch_bounds__(256) void k_transpose(const float* __restrict__ x,
                                                   u16* __restrict__ xT) {
  __shared__ float tile[32][33];
  int b = blockIdx.z;
  int n0 = blockIdx.x * 32, c0 = blockIdx.y * 32;
  int tx = threadIdx.x & 31, ty = threadIdx.x >> 5;  // 32 x 8
  const float* xb = x + (long)b * C * NN;
#pragma unroll
  for (int r = 0; r < 4; ++r)
    tile[ty + r * 8][tx] = xb[(long)(c0 + ty + r * 8) * NN + n0 + tx];
  __syncthreads();
  u16* xTb = xT + (long)b * NN * C;
#pragma unroll
  for (int r = 0; r < 4; ++r)
    xTb[(long)(n0 + ty + r * 8) * C + c0 + tx] = f2bf(tile[tx][ty + r * 8]);
}

// ---------- fp32 -> bf16 convert, all 4 weights in one launch ----------
__global__ __launch_bounds__(256) void k_cvt4(const float* __restrict__ s0,
                                              const float* __restrict__ s1,
                                              const float* __restrict__ s2,
                                              const float* __restrict__ s3,
                                              u16* __restrict__ d0, u16* __restrict__ d1,
                                              u16* __restrict__ d2, u16* __restrict__ d3) {
  int wsel = blockIdx.y;
  const float* s = wsel == 0 ? s0 : wsel == 1 ? s1 : wsel == 2 ? s2 : s3;
  u16* d = wsel == 0 ? d0 : wsel == 1 ? d1 : wsel == 2 ? d2 : d3;
  int i = blockIdx.x * 256 + threadIdx.x;
  d[i] = f2bf(s[i]);
}

// stage 64 rows x 256 u16 (global row stride 256) into LDS rows of 264 (pad 8)
DEV void stage_tile(const u16* __restrict__ g, u16* lds, int t) {
#pragma unroll
  for (int i = 0; i < 8; ++i) {
    int id = t + i * 256;
    int row = id >> 5, ch = id & 31;
    *reinterpret_cast<float4*>(lds + row * 264 + ch * 8) =
        *reinterpret_cast<const float4*>(g + row * 256 + ch * 8);
  }
}

// ---------- fused q/k/v projection ----------
__global__ __launch_bounds__(256) void k_qkv(
    const u16* __restrict__ xT, const u16* __restrict__ wqb, const u16* __restrict__ wkb,
    const u16* __restrict__ wvb, const float* __restrict__ bq, const float* __restrict__ bk,
    const float* __restrict__ bv, u16* __restrict__ qO, u16* __restrict__ kO,
    u16* __restrict__ vO) {
  __shared__ __align__(16) u16 Ash[64 * 264];
  __shared__ __align__(16) u16 Bsh[64 * 264];
  int t = threadIdx.x, w = t >> 6, lane = t & 63, lr = lane & 15, q = lane >> 4;
  int m0 = blockIdx.x * 64, n0 = blockIdx.y * 64, b = blockIdx.z;
  stage_tile(xT + (long)b * NN * C + (long)m0 * 256, Ash, t);
#pragma unroll 1
  for (int wsel = 0; wsel < 3; ++wsel) {
    const u16* wptr = wsel == 0 ? wqb : wsel == 1 ? wkb : wvb;
    stage_tile(wptr + (long)n0 * 256, Bsh, t);
    __syncthreads();
    v4f acc[4];
#pragma unroll
    for (int nt = 0; nt < 4; ++nt)
#pragma unroll
      for (int r = 0; r < 4; ++r) acc[nt][r] = 0.f;
#pragma unroll
    for (int ks = 0; ks < 8; ++ks) {
      v8bf a = *reinterpret_cast<const v8bf*>(Ash + (w * 16 + lr) * 264 + ks * 32 + q * 8);
#pragma unroll
      for (int nt = 0; nt < 4; ++nt) {
        v8bf bb = *reinterpret_cast<const v8bf*>(Bsh + (nt * 16 + lr) * 264 + ks * 32 + q * 8);
        acc[nt] = __builtin_amdgcn_mfma_f32_16x16x32_bf16(a, bb, acc[nt], 0, 0, 0);
      }
    }
    const float* bias = wsel == 0 ? bq : wsel == 1 ? bk : bv;
#pragma unroll
    for (int nt = 0; nt < 4; ++nt) {
#pragma unroll
      for (int r = 0; r < 4; ++r) {
        int gm = m0 + w * 16 + q * 4 + r;   // voxel
        int gn = n0 + nt * 16 + lr;         // out channel
        float val = acc[nt][r] + bias[gn];
        if (wsel == 0) {
          qO[((long)b * NN + gm) * C + gn] = f2bf(val * (0.0625f * LOG2E));
        } else if (wsel == 1) {
          kO[((long)b * NN + gm) * C + gn] = f2bf(val);
        } else {
          vO[(long)b * C * NN + (long)gn * NN + gm] = f2bf(val);
        }
      }
    }
    __syncthreads();
  }
}

// ---------- generic C[m,n'] = scale*(sum_k A[m,k]B[n',k] + bias) (+resid) ----------
__global__ __launch_bounds__(256) void k_gemm(
    const u16* __restrict__ A, long aStr, const u16* __restrict__ Bm, long bStr,
    const float* __restrict__ biasM, const float* __restrict__ biasN,
    const float* __restrict__ resid, long rStr, float scale,
    float* __restrict__ outF, u16* __restrict__ outH, long oStr, int ldm, int ldn) {
  __shared__ __align__(16) u16 Ash[64 * 264];
  __shared__ __align__(16) u16 Bsh[64 * 264];
  int t = threadIdx.x;
  int w = t >> 6, lane = t & 63, lr = lane & 15, q = lane >> 4;
  int m0 = blockIdx.x * 64, n0 = blockIdx.y * 64, b = blockIdx.z;
  stage_tile(A + b * aStr + (long)m0 * 256, Ash, t);
  stage_tile(Bm + b * bStr + (long)n0 * 256, Bsh, t);
  __syncthreads();
  v4f acc[4];
#pragma unroll
  for (int nt = 0; nt < 4; ++nt)
#pragma unroll
    for (int r = 0; r < 4; ++r) acc[nt][r] = 0.f;
#pragma unroll
  for (int ks = 0; ks < 8; ++ks) {
    v8bf a = *reinterpret_cast<const v8bf*>(Ash + (w * 16 + lr) * 264 + ks * 32 + q * 8);
#pragma unroll
    for (int nt = 0; nt < 4; ++nt) {
      v8bf bb = *reinterpret_cast<const v8bf*>(Bsh + (nt * 16 + lr) * 264 + ks * 32 + q * 8);
      acc[nt] = __builtin_amdgcn_mfma_f32_16x16x32_bf16(a, bb, acc[nt], 0, 0, 0);
    }
  }
#pragma unroll
  for (int nt = 0; nt < 4; ++nt) {
#pragma unroll
    for (int r = 0; r < 4; ++r) {
      int gm = m0 + w * 16 + q * 4 + r;
      int gn = n0 + nt * 16 + lr;
      float val = acc[nt][r];
      if (biasM) val += biasM[gm];
      if (biasN) val += biasN[gn];
      val *= scale;
      long addr = b * oStr + (long)gm * ldm + (long)gn * ldn;
      if (resid) val += resid[b * rStr + (long)gm * ldm + (long)gn * ldn];
      if (outF) outF[addr] = val;
      else outH[addr] = f2bf(val);
    }
  }
}

// ---------- flash attention, BN=32, split-j js-way, log2-domain softmax ----------
// qT,kT: (B,N,C) bf16 (q pre-scaled by C^-0.5*log2e); V: (B,C,N) bf16
// op_h: (B,N,C) bf16 normalized partials; ml: (js,B,N,2) fp32 {m,l}
__global__ __launch_bounds__(256, 3) void k_flash(const u16* __restrict__ qT,
                                                  const u16* __restrict__ kT,
                                                  const u16* __restrict__ V,
                                                  u16* __restrict__ op0,
                                                  u16* __restrict__ op1,
                                                  u16* __restrict__ op2,
                                                  u16* __restrict__ op3,
                                                  float* __restrict__ ml, int span) {
  __shared__ __align__(16) u16 ksh[32 * 256];   // 32 j-rows x 32 chunks (XOR-swizzled)
  __shared__ __align__(16) u16 vsh[256 * 32];   // 256 c-rows x 4 chunks (XOR-swizzled)
  __shared__ __align__(16) u16 psh[4 * 16 * 40];
  int t = threadIdx.x;
  int w = t >> 6, lane = t & 63, lr = lane & 15, q = lane >> 4;
  int b = blockIdx.z, h = blockIdx.y;
  int i0 = blockIdx.x * 64;
  const u16* qb = qT + ((long)b * NN + i0 + w * 16) * C;
  const u16* kb = kT + (long)b * NN * C;
  const u16* vb = V + (long)b * C * NN;

  v8bf qf[8];
#pragma unroll
  for (int ks = 0; ks < 8; ++ks)
    qf[ks] = *reinterpret_cast<const v8bf*>(qb + lr * C + ks * 32 + q * 8);

  v4f accO[16];
#pragma unroll
  for (int ct = 0; ct < 16; ++ct)
#pragma unroll
    for (int r = 0; r < 4; ++r) accO[ct][r] = 0.f;
  float mst[4], lst[4];
#pragma unroll
  for (int r = 0; r < 4; ++r) { mst[r] = -3.0e38f; lst[r] = 0.f; }

  u16* pw = psh + w * (16 * 40);
  const int xl = lr & 7;

  int jend = h * span + span;
  for (int j0 = h * span; j0 < jend; j0 += 32) {
    __syncthreads();  // prev iter's LDS reads done before DMA overwrite
#pragma unroll
    for (int i = 0; i < 4; ++i) {
      int idx = w * 4 + i;                    // 0..15, 1KB per dma16 wave-op
      int kr = idx * 2 + (lane >> 5);         // 0..31
      int kc = (lane & 31) ^ (kr & 7);
      dma16(kb + (long)(j0 + kr) * 256 + kc * 8, ksh + idx * 512);
      int vr = idx * 16 + (lane >> 2);        // 0..255
      int vc = (lane & 3) ^ (vr & 3);
      dma16(vb + (long)vr * NN + j0 + vc * 8, vsh + idx * 512);
    }
    __syncthreads();  // vmcnt(0) drain + barrier

    v4f s[2];
#pragma unroll
    for (int jt = 0; jt < 2; ++jt)
#pragma unroll
      for (int r = 0; r < 4; ++r) s[jt][r] = 0.f;
#pragma unroll
    for (int ks = 0; ks < 8; ++ks) {
#pragma unroll
      for (int jt = 0; jt < 2; ++jt) {
        v8bf kf = *reinterpret_cast<const v8bf*>(
            ksh + (jt * 16 + lr) * 256 + (((ks * 4 + q) ^ xl) << 3));
        s[jt] = __builtin_amdgcn_mfma_f32_16x16x32_bf16(qf[ks], kf, s[jt], 0, 0, 0);
      }
    }

    // online softmax (log2 domain; scale*log2e folded into q)
    float al[4];
#pragma unroll
    for (int r = 0; r < 4; ++r) {
      float mx = fmaxf(s[0][r], s[1][r]);
#pragma unroll
      for (int d = 1; d < 16; d <<= 1) mx = fmaxf(mx, __shfl_xor(mx, d, 64));
      float mn = fmaxf(mst[r], mx);
      al[r] = exp2f(mst[r] - mn);
      mst[r] = mn;
    }
#pragma unroll
    for (int r = 0; r < 4; ++r) {
      float rs = 0.f;
#pragma unroll
      for (int jt = 0; jt < 2; ++jt) {
        float p = exp2f(s[jt][r] - mst[r]);
        s[jt][r] = p;
        rs += p;
      }
#pragma unroll
      for (int d = 1; d < 16; d <<= 1) rs += __shfl_xor(rs, d, 64);
      lst[r] = lst[r] * al[r] + rs;
    }
    bool chg = (al[0] != 1.f) || (al[1] != 1.f) || (al[2] != 1.f) || (al[3] != 1.f);
    if (__any(chg)) {
#pragma unroll
      for (int ct = 0; ct < 16; ++ct)
#pragma unroll
        for (int r = 0; r < 4; ++r) accO[ct][r] *= al[r];
    }

    // P: C/D layout -> per-wave LDS region -> A layout (no barrier: same wave)
#pragma unroll
    for (int jt = 0; jt < 2; ++jt)
#pragma unroll
      for (int r = 0; r < 4; ++r)
        pw[(q * 4 + r) * 40 + jt * 16 + lr] = f2bf(s[jt][r]);
    asm volatile("s_waitcnt lgkmcnt(0)" ::: "memory");  // DS pipe in-order per wave

    v8bf pa = *reinterpret_cast<const v8bf*>(pw + lr * 40 + q * 8);
#pragma unroll
    for (int ct = 0; ct < 16; ++ct) {
      v8bf v0 = *reinterpret_cast<const v8bf*>(
          vsh + (ct * 16 + lr) * 32 + ((q ^ (lr & 3)) << 3));
      accO[ct] = __builtin_amdgcn_mfma_f32_16x16x32_bf16(pa, v0, accO[ct], 0, 0, 0);
    }
  }

  float inv[4];
#pragma unroll
  for (int r = 0; r < 4; ++r) inv[r] = 1.0f / lst[r];
  u16* opp = h == 0 ? op0 : h == 1 ? op1 : h == 2 ? op2 : op3;
  u16* ob = opp + ((long)b * NN + i0 + w * 16) * C;
#pragma unroll
  for (int ct = 0; ct < 16; ++ct)
#pragma unroll
    for (int r = 0; r < 4; ++r)
      ob[(q * 4 + r) * C + ct * 16 + lr] = f2bf(accO[ct][r] * inv[r]);
  if (lr == 0) {
    long rbase = ((long)h * CB + b) * NN + i0 + w * 16 + q * 4;
#pragma unroll
    for (int r = 0; r < 4; ++r) {
      ml[(rbase + r) * 2] = mst[r];
      ml[(rbase + r) * 2 + 1] = lst[r];
    }
  }
}

// ---------- merge the js j-part partials ----------
__global__ __launch_bounds__(256) void k_combine(const u16* __restrict__ p0,
                                                 const u16* __restrict__ p1,
                                                 const u16* __restrict__ p2,
                                                 const u16* __restrict__ p3,
                                                 const float* __restrict__ ml,
                                                 u16* __restrict__ o, int js) {
  long row = (long)blockIdx.x * 8 + (threadIdx.x >> 5);
  int tc = (threadIdx.x & 31) * 8;
  float m[4], l[4];
  float mx = -3.0e38f;
  for (int h = 0; h < js; ++h) {
    m[h] = ml[((long)h * CB * NN + row) * 2];
    l[h] = ml[((long)h * CB * NN + row) * 2 + 1];
    mx = fmaxf(mx, m[h]);
  }
  float tot = 0.f, a[4];
  for (int h = 0; h < js; ++h) { a[h] = exp2f(m[h] - mx) * l[h]; tot += a[h]; }
  float inv = 1.f / tot;
  float acc[8];
#pragma unroll
  for (int i = 0; i < 8; ++i) acc[i] = 0.f;
  const u16* ps[4] = {p0, p1, p2, p3};
  for (int h = 0; h < js; ++h) {
    uint4 u = *reinterpret_cast<const uint4*>(ps[h] + row * C + tc);
    const u16* p = reinterpret_cast<const u16*>(&u);
    float wgt = a[h] * inv;
#pragma unroll
    for (int i = 0; i < 8; ++i) acc[i] += wgt * bf2f(p[i]);
  }
  u16 outv[8];
#pragma unroll
  for (int i = 0; i < 8; ++i) outv[i] = f2bf(acc[i]);
  *reinterpret_cast<uint4*>(o + row * C + tc) = *reinterpret_cast<const uint4*>(outv);
}

extern "C" void kernel_launch(void* const* d_in, const int* in_sizes, int n_in,
                              void* d_out, int out_size, void* d_ws, size_t ws_size,
                              hipStream_t stream) {
  const float* x = (const float*)d_in[0];
  const float* wq = (const float*)d_in[1];
  const float* bq = (const float*)d_in[2];
  const float* wk = (const float*)d_in[3];
  const float* bk = (const float*)d_in[4];
  const float* wv = (const float*)d_in[5];
  const float* bv = (const float*)d_in[6];
  const float* wp = (const float*)d_in[7];
  const float* bp = (const float*)d_in[8];
  float* out = (float*)d_out;
  char* ws = (char*)d_ws;

  const long SLOT = 8388608L;
  const size_t NEED4 = 524288UL + 7 * 8388608UL + 524288UL;
  int js = (ws_size >= NEED4) ? 4 : 2;

  u16* wqb = (u16*)(ws + 0);
  u16* wkb = (u16*)(ws + 131072L);
  u16* wvb = (u16*)(ws + 262144L);
  u16* wpb = (u16*)(ws + 393216L);
  char* base = ws + 524288L;
  u16* xT  = (u16*)(base);                 // slot0: xT, later op0
  u16* qTw = (u16*)(base + 1 * SLOT);      // slot1: q, later combined O
  u16* kTw = (u16*)(base + 2 * SLOT);      // slot2: k
  u16* vw  = (u16*)(base + 3 * SLOT);      // slot3: v
  u16* op1 = (u16*)(base + 4 * SLOT);      // slot4
  u16* op2 = js == 4 ? (u16*)(base + 5 * SLOT) : op1;  // unused when js==2
  u16* op3 = js == 4 ? (u16*)(base + 6 * SLOT) : op1;  // unused when js==2
  float* ml = (float*)(base + (js == 4 ? 7 : 5) * SLOT);
  u16* op0 = xT;    // xT dead after k_qkv
  u16* oW  = qTw;   // q dead after k_flash

  k_cvt4<<<dim3(256, 4), 256, 0, stream>>>(wq, wk, wv, wp, wqb, wkb, wvb, wpb);
  k_transpose<<<dim3(128, 8, CB), 256, 0, stream>>>(x, xT);
  k_qkv<<<dim3(64, 4, CB), 256, 0, stream>>>(xT, wqb, wkb, wvb, bq, bk, bv, qTw, kTw, vw);
  k_flash<<<dim3(64, js, CB), 256, 0, stream>>>(qTw, kTw, vw, op0, op1, op2, op3, ml,
                                                NN / js);
  k_combine<<<2048, 256, 0, stream>>>(op0, op1, op2, op3, ml, oW, js);

  long nc = (long)NN * C;
  k_gemm<<<dim3(4, 64, CB), 256, 0, stream>>>(wpb, 0, oW, nc, bp, nullptr, x, nc,
                                              1.0f, out, nullptr, nc, NN, 1);
}

// Round 4
// 274.001 us; speedup vs baseline: 1.2422x; 1.2422x over previous
//
#include <hip/hip_runtime.h>

typedef unsigned short u16;
typedef unsigned int u32;
typedef __bf16 v8bf __attribute__((ext_vector_type(8)));
typedef float v4f __attribute__((ext_vector_type(4)));

#define DEV __device__ __forceinline__

constexpr int CB = 4;     // batch
constexpr int C = 256;    // channels
constexpr int NN = 4096;  // voxels
constexpr float LOG2E = 1.4426950408889634f;

DEV u16 f2bf(float f) {
  union { float f; u32 u; } v; v.f = f;
  u32 r = v.u + 0x7fffu + ((v.u >> 16) & 1u);  // RNE
  return (u16)(r >> 16);
}
DEV float bf2f(u16 h) {
  union { u32 u; float f; } v; v.u = ((u32)h) << 16; return v.f;
}

// async global->LDS DMA, 16B per lane; LDS dest = wave-uniform base + lane*16
DEV void dma16(const u16* g, const u16* lds_base) {
  __builtin_amdgcn_global_load_lds(
      (const __attribute__((address_space(1))) void*)(unsigned long long)g,
      (__attribute__((address_space(3))) void*)(u32)(unsigned long long)lds_base,
      16, 0, 0);
}

// ---------- transpose + bf16 convert: xT[b][n][c] = bf16(x[b][c][n]) ----------
__global__ __launch_bounds__(256) void k_transpose(const float* __restrict__ x,
                                                   u16* __restrict__ xT) {
  __shared__ float tile[32][33];
  int b = blockIdx.z;
  int n0 = blockIdx.x * 32, c0 = blockIdx.y * 32;
  int tx = threadIdx.x & 31, ty = threadIdx.x >> 5;  // 32 x 8
  const float* xb = x + (long)b * C * NN;
#pragma unroll
  for (int r = 0; r < 4; ++r)
    tile[ty + r * 8][tx] = xb[(long)(c0 + ty + r * 8) * NN + n0 + tx];
  __syncthreads();
  u16* xTb = xT + (long)b * NN * C;
#pragma unroll
  for (int r = 0; r < 4; ++r)
    xTb[(long)(n0 + ty + r * 8) * C + c0 + tx] = f2bf(tile[tx][ty + r * 8]);
}

// ---------- fp32 -> bf16 convert (4 weights) + zero the norm buffer ----------
__global__ __launch_bounds__(256) void k_cvt4(const float* __restrict__ s0,
                                              const float* __restrict__ s1,
                                              const float* __restrict__ s2,
                                              const float* __restrict__ s3,
                                              u16* __restrict__ d0, u16* __restrict__ d1,
                                              u16* __restrict__ d2, u16* __restrict__ d3,
                                              float* __restrict__ Mbuf) {
  if (blockIdx.x == 0 && blockIdx.y == 0 && threadIdx.x < 8) Mbuf[threadIdx.x] = 0.f;
  int wsel = blockIdx.y;
  const float* s = wsel == 0 ? s0 : wsel == 1 ? s1 : wsel == 2 ? s2 : s3;
  u16* d = wsel == 0 ? d0 : wsel == 1 ? d1 : wsel == 2 ? d2 : d3;
  int i = blockIdx.x * 256 + threadIdx.x;
  d[i] = f2bf(s[i]);
}

// stage 64 rows x 256 u16 (global row stride 256) into LDS rows of 264 (pad 8)
DEV void stage_tile(const u16* __restrict__ g, u16* lds, int t) {
#pragma unroll
  for (int i = 0; i < 8; ++i) {
    int id = t + i * 256;
    int row = id >> 5, ch = id & 31;
    *reinterpret_cast<float4*>(lds + row * 264 + ch * 8) =
        *reinterpret_cast<const float4*>(g + row * 256 + ch * 8);
  }
}

// ---------- fused q/k/v projection ----------
__global__ __launch_bounds__(256) void k_qkv(
    const u16* __restrict__ xT, const u16* __restrict__ wqb, const u16* __restrict__ wkb,
    const u16* __restrict__ wvb, const float* __restrict__ bq, const float* __restrict__ bk,
    const float* __restrict__ bv, u16* __restrict__ qO, u16* __restrict__ kO,
    u16* __restrict__ vO) {
  __shared__ __align__(16) u16 Ash[64 * 264];
  __shared__ __align__(16) u16 Bsh[64 * 264];
  int t = threadIdx.x, w = t >> 6, lane = t & 63, lr = lane & 15, q = lane >> 4;
  int m0 = blockIdx.x * 64, n0 = blockIdx.y * 64, b = blockIdx.z;
  stage_tile(xT + (long)b * NN * C + (long)m0 * 256, Ash, t);
#pragma unroll 1
  for (int wsel = 0; wsel < 3; ++wsel) {
    const u16* wptr = wsel == 0 ? wqb : wsel == 1 ? wkb : wvb;
    stage_tile(wptr + (long)n0 * 256, Bsh, t);
    __syncthreads();
    v4f acc[4];
#pragma unroll
    for (int nt = 0; nt < 4; ++nt)
#pragma unroll
      for (int r = 0; r < 4; ++r) acc[nt][r] = 0.f;
#pragma unroll
    for (int ks = 0; ks < 8; ++ks) {
      v8bf a = *reinterpret_cast<const v8bf*>(Ash + (w * 16 + lr) * 264 + ks * 32 + q * 8);
#pragma unroll
      for (int nt = 0; nt < 4; ++nt) {
        v8bf bb = *reinterpret_cast<const v8bf*>(Bsh + (nt * 16 + lr) * 264 + ks * 32 + q * 8);
        acc[nt] = __builtin_amdgcn_mfma_f32_16x16x32_bf16(a, bb, acc[nt], 0, 0, 0);
      }
    }
    const float* bias = wsel == 0 ? bq : wsel == 1 ? bk : bv;
#pragma unroll
    for (int nt = 0; nt < 4; ++nt) {
#pragma unroll
      for (int r = 0; r < 4; ++r) {
        int gm = m0 + w * 16 + q * 4 + r;   // voxel
        int gn = n0 + nt * 16 + lr;         // out channel
        float val = acc[nt][r] + bias[gn];
        if (wsel == 0) {
          qO[((long)b * NN + gm) * C + gn] = f2bf(val * (0.0625f * LOG2E));
        } else if (wsel == 1) {
          kO[((long)b * NN + gm) * C + gn] = f2bf(val);
        } else {
          vO[(long)b * C * NN + (long)gn * NN + gm] = f2bf(val);
        }
      }
    }
    __syncthreads();
  }
}

// ---------- per-batch max row-norm^2 of q' and k (Cauchy-Schwarz bound) ----------
__global__ __launch_bounds__(256) void k_maxnorm(const u16* __restrict__ qT,
                                                 const u16* __restrict__ kT,
                                                 float* __restrict__ Mbuf) {
  int b = blockIdx.z, tsel = blockIdx.y;
  const u16* src = (tsel ? kT : qT) + (long)b * NN * C;
  int row = blockIdx.x * 64 + (threadIdx.x >> 2);
  const uint4* pp =
      reinterpret_cast<const uint4*>(src + (long)row * C + (threadIdx.x & 3) * 64);
  float s = 0.f;
#pragma unroll
  for (int u = 0; u < 8; ++u) {
    uint4 d = pp[u];
    const u16* e = reinterpret_cast<const u16*>(&d);
#pragma unroll
    for (int i = 0; i < 8; ++i) { float f = bf2f(e[i]); s += f * f; }
  }
  s += __shfl_xor(s, 1, 64);
  s += __shfl_xor(s, 2, 64);
#pragma unroll
  for (int d2 = 4; d2 < 64; d2 <<= 1) s = fmaxf(s, __shfl_xor(s, d2, 64));
  if ((threadIdx.x & 63) == 0)
    atomicMax((u32*)(Mbuf + tsel * 4 + b), __float_as_uint(s));
}

// ---------- generic C[m,n'] = scale*(sum_k A[m,k]B[n',k] + bias) (+resid) ----------
__global__ __launch_bounds__(256) void k_gemm(
    const u16* __restrict__ A, long aStr, const u16* __restrict__ Bm, long bStr,
    const float* __restrict__ biasM, const float* __restrict__ biasN,
    const float* __restrict__ resid, long rStr, float scale,
    float* __restrict__ outF, u16* __restrict__ outH, long oStr, int ldm, int ldn) {
  __shared__ __align__(16) u16 Ash[64 * 264];
  __shared__ __align__(16) u16 Bsh[64 * 264];
  int t = threadIdx.x;
  int w = t >> 6, lane = t & 63, lr = lane & 15, q = lane >> 4;
  int m0 = blockIdx.x * 64, n0 = blockIdx.y * 64, b = blockIdx.z;
  stage_tile(A + b * aStr + (long)m0 * 256, Ash, t);
  stage_tile(Bm + b * bStr + (long)n0 * 256, Bsh, t);
  __syncthreads();
  v4f acc[4];
#pragma unroll
  for (int nt = 0; nt < 4; ++nt)
#pragma unroll
    for (int r = 0; r < 4; ++r) acc[nt][r] = 0.f;
#pragma unroll
  for (int ks = 0; ks < 8; ++ks) {
    v8bf a = *reinterpret_cast<const v8bf*>(Ash + (w * 16 + lr) * 264 + ks * 32 + q * 8);
#pragma unroll
    for (int nt = 0; nt < 4; ++nt) {
      v8bf bb = *reinterpret_cast<const v8bf*>(Bsh + (nt * 16 + lr) * 264 + ks * 32 + q * 8);
      acc[nt] = __builtin_amdgcn_mfma_f32_16x16x32_bf16(a, bb, acc[nt], 0, 0, 0);
    }
  }
#pragma unroll
  for (int nt = 0; nt < 4; ++nt) {
#pragma unroll
    for (int r = 0; r < 4; ++r) {
      int gm = m0 + w * 16 + q * 4 + r;
      int gn = n0 + nt * 16 + lr;
      float val = acc[nt][r];
      if (biasM) val += biasM[gm];
      if (biasN) val += biasN[gn];
      val *= scale;
      long addr = b * oStr + (long)gm * ldm + (long)gn * ldn;
      if (resid) val += resid[b * rStr + (long)gm * ldm + (long)gn * ldn];
      if (outF) outF[addr] = val;
      else outH[addr] = f2bf(val);
    }
  }
}

// issue the 8 DMAs for one 32-j tile (this wave's quarter)
DEV void flash_issue(const u16* kb, const u16* vb, const u16* kshb, const u16* vshb,
                     int j0, int w, int lane) {
#pragma unroll
  for (int i = 0; i < 4; ++i) {
    int idx = w * 4 + i;
    int kr = idx * 2 + (lane >> 5);
    int kc = (lane & 31) ^ (kr & 7);
    dma16(kb + (long)(j0 + kr) * 256 + kc * 8, kshb + idx * 512);
  }
#pragma unroll
  for (int i = 0; i < 4; ++i) {
    int idx = w * 4 + i;
    int vr = idx * 16 + (lane >> 2);
    int vc = (lane & 3) ^ ((vr ^ (vr >> 2)) & 3);
    dma16(vb + (long)vr * NN + j0 + vc * 8, vshb + idx * 512);
  }
}

// ---------- flash attention: fixed-bound softmax, dbuf DMA, no vmcnt(0) drain ----
// qT,kT: (B,N,C) bf16 (q pre-scaled by C^-0.5*log2e); V: (B,C,N) bf16
__global__ __launch_bounds__(256, 2) void k_flash(const u16* __restrict__ qT,
                                                  const u16* __restrict__ kT,
                                                  const u16* __restrict__ V,
                                                  u16* __restrict__ op0,
                                                  u16* __restrict__ op1,
                                                  u16* __restrict__ op2,
                                                  u16* __restrict__ op3,
                                                  float* __restrict__ ml,
                                                  const float* __restrict__ Mbuf,
                                                  int span) {
  __shared__ __align__(16) u16 ksh[2][32 * 256];   // 16 KB each, XOR-swizzled
  __shared__ __align__(16) u16 vsh[2][256 * 32];   // 16 KB each, XOR-swizzled
  __shared__ __align__(16) u16 psh[4 * 16 * 40];   // per-wave P region
  int t = threadIdx.x;
  int w = t >> 6, lane = t & 63, lr = lane & 15, q = lane >> 4;
  int b = blockIdx.z, h = blockIdx.y;
  int i0 = blockIdx.x * 64;
  const u16* qb = qT + ((long)b * NN + i0 + w * 16) * C;
  const u16* kb = kT + (long)b * NN * C;
  const u16* vb = V + (long)b * C * NN;
  // Cauchy-Schwarz upper bound on scores (log2 units); +1 for bf16 rounding slack
  float M = sqrtf(Mbuf[b] * Mbuf[4 + b]) + 1.0f;

  v8bf qf[8];
#pragma unroll
  for (int ks = 0; ks < 8; ++ks)
    qf[ks] = *reinterpret_cast<const v8bf*>(qb + lr * C + ks * 32 + q * 8);

  v4f accO[16];
#pragma unroll
  for (int ct = 0; ct < 16; ++ct)
#pragma unroll
    for (int r = 0; r < 4; ++r) accO[ct][r] = 0.f;
  float lsum[4] = {0.f, 0.f, 0.f, 0.f};

  u16* pw = psh + w * 640;
  const int xk = lr & 7;
  const int xv = (lr ^ (lr >> 2)) & 3;

  int jstart = h * span;
  int niter = span >> 5;
  flash_issue(kb, vb, ksh[0], vsh[0], jstart, w, lane);
  int cur = 0;
#pragma unroll 1
  for (int it = 0; it < niter; ++it) {
    int j0 = jstart + (it << 5);
    int jn = (it + 1 < niter) ? j0 + 32 : jstart;
    // (A) all waves done reading the buffer we are about to overwrite
    asm volatile("s_waitcnt lgkmcnt(0)\n\ts_barrier" ::: "memory");
    flash_issue(kb, vb, ksh[cur ^ 1], vsh[cur ^ 1], jn, w, lane);
    // (B) current tile's DMA (8 oldest) complete, next 8 stay in flight
    asm volatile("s_waitcnt vmcnt(8)\n\ts_barrier" ::: "memory");

    const u16* kcur = ksh[cur];
    const u16* vcur = vsh[cur];
    v4f s[2];
#pragma unroll
    for (int jt = 0; jt < 2; ++jt)
#pragma unroll
      for (int r = 0; r < 4; ++r) s[jt][r] = 0.f;
#pragma unroll
    for (int ks = 0; ks < 8; ++ks) {
#pragma unroll
      for (int jt = 0; jt < 2; ++jt) {
        v8bf kf = *reinterpret_cast<const v8bf*>(
            kcur + (jt * 16 + lr) * 256 + (((ks * 4 + q) ^ xk) << 3));
        s[jt] = __builtin_amdgcn_mfma_f32_16x16x32_bf16(qf[ks], kf, s[jt], 0, 0, 0);
      }
    }

    // p = 2^(s - M); purely local l accumulation, no cross-lane work per iter
#pragma unroll
    for (int jt = 0; jt < 2; ++jt) {
#pragma unroll
      for (int r = 0; r < 4; ++r) {
        float p = exp2f(s[jt][r] - M);
        lsum[r] += p;
        u32 pb = (__float_as_uint(p) + 0x8000u) >> 16;  // ~RNE bf16
        pw[(q * 4 + r) * 40 + jt * 16 + lr] = (u16)pb;
      }
    }
    asm volatile("s_waitcnt lgkmcnt(0)" ::: "memory");  // same-wave P write->read
    v8bf pa = *reinterpret_cast<const v8bf*>(pw + lr * 40 + q * 8);
#pragma unroll
    for (int ct = 0; ct < 16; ++ct) {
      v8bf v0 = *reinterpret_cast<const v8bf*>(
          vcur + (ct * 16 + lr) * 32 + ((q ^ xv) << 3));
      accO[ct] = __builtin_amdgcn_mfma_f32_16x16x32_bf16(pa, v0, accO[ct], 0, 0, 0);
    }
    cur ^= 1;
  }

  // one-time row-sum reduce across the 16 lanes sharing q
#pragma unroll
  for (int r = 0; r < 4; ++r) {
#pragma unroll
    for (int d = 1; d < 16; d <<= 1) lsum[r] += __shfl_xor(lsum[r], d, 64);
  }
  float inv[4];
#pragma unroll
  for (int r = 0; r < 4; ++r) inv[r] = 1.0f / lsum[r];
  u16* opp = h == 0 ? op0 : h == 1 ? op1 : h == 2 ? op2 : op3;
  u16* ob = opp + ((long)b * NN + i0 + w * 16) * C;
#pragma unroll
  for (int ct = 0; ct < 16; ++ct)
#pragma unroll
    for (int r = 0; r < 4; ++r)
      ob[(q * 4 + r) * C + ct * 16 + lr] = f2bf(accO[ct][r] * inv[r]);
  if (lr == 0) {
    long rbase = ((long)h * CB + b) * NN + i0 + w * 16 + q * 4;
#pragma unroll
    for (int r = 0; r < 4; ++r) {
      ml[(rbase + r) * 2] = M;          // common bound => combine weights = l_h
      ml[(rbase + r) * 2 + 1] = lsum[r];
    }
  }
}

// ---------- merge the js j-part partials ----------
__global__ __launch_bounds__(256) void k_combine(const u16* __restrict__ p0,
                                                 const u16* __restrict__ p1,
                                                 const u16* __restrict__ p2,
                                                 const u16* __restrict__ p3,
                                                 const float* __restrict__ ml,
                                                 u16* __restrict__ o, int js) {
  long row = (long)blockIdx.x * 8 + (threadIdx.x >> 5);
  int tc = (threadIdx.x & 31) * 8;
  float m[4], l[4];
  float mx = -3.0e38f;
  for (int h = 0; h < js; ++h) {
    m[h] = ml[((long)h * CB * NN + row) * 2];
    l[h] = ml[((long)h * CB * NN + row) * 2 + 1];
    mx = fmaxf(mx, m[h]);
  }
  float tot = 0.f, a[4];
  for (int h = 0; h < js; ++h) { a[h] = exp2f(m[h] - mx) * l[h]; tot += a[h]; }
  float inv = 1.f / tot;
  float acc[8];
#pragma unroll
  for (int i = 0; i < 8; ++i) acc[i] = 0.f;
  const u16* ps[4] = {p0, p1, p2, p3};
  for (int h = 0; h < js; ++h) {
    uint4 u = *reinterpret_cast<const uint4*>(ps[h] + row * C + tc);
    const u16* p = reinterpret_cast<const u16*>(&u);
    float wgt = a[h] * inv;
#pragma unroll
    for (int i = 0; i < 8; ++i) acc[i] += wgt * bf2f(p[i]);
  }
  u16 outv[8];
#pragma unroll
  for (int i = 0; i < 8; ++i) outv[i] = f2bf(acc[i]);
  *reinterpret_cast<uint4*>(o + row * C + tc) = *reinterpret_cast<const uint4*>(outv);
}

extern "C" void kernel_launch(void* const* d_in, const int* in_sizes, int n_in,
                              void* d_out, int out_size, void* d_ws, size_t ws_size,
                              hipStream_t stream) {
  const float* x = (const float*)d_in[0];
  const float* wq = (const float*)d_in[1];
  const float* bq = (const float*)d_in[2];
  const float* wk = (const float*)d_in[3];
  const float* bk = (const float*)d_in[4];
  const float* wv = (const float*)d_in[5];
  const float* bv = (const float*)d_in[6];
  const float* wp = (const float*)d_in[7];
  const float* bp = (const float*)d_in[8];
  float* out = (float*)d_out;
  char* ws = (char*)d_ws;

  const long SLOT = 8388608L;
  const size_t NEED4 = 524288UL + 7 * 8388608UL + 524288UL + 4096UL;
  int js = (ws_size >= NEED4) ? 4 : 2;

  u16* wqb = (u16*)(ws + 0);
  u16* wkb = (u16*)(ws + 131072L);
  u16* wvb = (u16*)(ws + 262144L);
  u16* wpb = (u16*)(ws + 393216L);
  char* base = ws + 524288L;
  u16* xT  = (u16*)(base);                 // slot0: xT, later op0
  u16* qTw = (u16*)(base + 1 * SLOT);      // slot1: q, later combined O
  u16* kTw = (u16*)(base + 2 * SLOT);      // slot2: k
  u16* vw  = (u16*)(base + 3 * SLOT);      // slot3: v
  u16* op1 = (u16*)(base + 4 * SLOT);      // slot4
  u16* op2 = js == 4 ? (u16*)(base + 5 * SLOT) : op1;
  u16* op3 = js == 4 ? (u16*)(base + 6 * SLOT) : op1;
  float* ml = (float*)(base + (js == 4 ? 7 : 5) * SLOT);   // 512 KB max
  float* Mbuf = ml + 131072;                               // 8 floats
  u16* op0 = xT;    // xT dead after k_qkv
  u16* oW  = qTw;   // q dead after k_flash

  k_cvt4<<<dim3(256, 4), 256, 0, stream>>>(wq, wk, wv, wp, wqb, wkb, wvb, wpb, Mbuf);
  k_transpose<<<dim3(128, 8, CB), 256, 0, stream>>>(x, xT);
  k_qkv<<<dim3(64, 4, CB), 256, 0, stream>>>(xT, wqb, wkb, wvb, bq, bk, bv, qTw, kTw, vw);
  k_maxnorm<<<dim3(64, 2, CB), 256, 0, stream>>>(qTw, kTw, Mbuf);
  k_flash<<<dim3(64, js, CB), 256, 0, stream>>>(qTw, kTw, vw, op0, op1, op2, op3, ml,
                                                Mbuf, NN / js);
  k_combine<<<2048, 256, 0, stream>>>(op0, op1, op2, op3, ml, oW, js);

  long nc = (long)NN * C;
  k_gemm<<<dim3(4, 64, CB), 256, 0, stream>>>(wpb, 0, oW, nc, bp, nullptr, x, nc,
                                              1.0f, out, nullptr, nc, NN, 1);
}